// Round 10
// baseline (45.403 us; speedup 1.0000x reference)
//
#include <hip/hip_runtime.h>
#include <hip/hip_bf16.h>
#include <stdint.h>

// ---------------------------------------------------------------------------
// GraphicalBranch: out[r] = relu(x[row_r] @ W_self + (S_{b_r} @ W_nbr) + bias)
//   S_b = sum of the 28 pair-node rows of sample b
//   row_r = b*28 + pidx(pmin,pmax), pidx = 7i - i(i-1)/2 + (j-i-1)  [analytic]
// K1 prep (1536 blks): streaming S-sum -> Sbf (bf16) | W^T -> bf16.  NO Abf.
// K2 fused GEMM (128x8 blks, 64-col tiles, 5 blocks/CU):
//   A gathered DIRECTLY from x (L3-resident after prep) with in-register
//   f32->bf16 convert + swizzled ds_write; B (W^T tiles) via global_load_lds.
//   Same-bx blocks land on one XCD (grid-x stride % 8 == 0) -> gather L2-local.
//   Strips 0..4 = 80 rel rows (@Wself^T); strip 5 = 8 S rows dup (@Wnbr^T->T).
//   Epilogue: out = relu(acc + T[sample] + bias).
// ---------------------------------------------------------------------------

typedef __bf16 bf16_t;
typedef __bf16 bf16x8 __attribute__((ext_vector_type(8)));
typedef __bf16 bf16x4 __attribute__((ext_vector_type(4)));
typedef float  f32x4  __attribute__((ext_vector_type(4)));

#define D_DIM 512
#define NC2   28
#define NOBJ  8
#define MAXREL 10
#define B_SAMP 1024
#define OUTROWS (B_SAMP * MAXREL)

__device__ __forceinline__ void gload_lds16(const void* g, void* l) {
  __builtin_amdgcn_global_load_lds(
      (const __attribute__((address_space(1))) unsigned int*)g,
      (__attribute__((address_space(3))) unsigned int*)l, 16, 0, 0);
}

// --- K1: prep --------------------------------------------------------------
// blocks [0,1024):     S[b] = sum of 28 rows (streaming float4) -> bf16
// blocks [1024,1536):  W transpose+convert (256 blocks per matrix)
__global__ __launch_bounds__(256) void prep_kernel(
    const float* __restrict__ x, const float* __restrict__ Wself,
    const float* __restrict__ Wnbr,
    bf16_t* __restrict__ Sbf, bf16_t* __restrict__ Wst, bf16_t* __restrict__ Wnt)
{
  const int blk = blockIdx.x, tid = threadIdx.x;
  if (blk < B_SAMP) {
    __shared__ float4 oddsum[128];
    const int h = tid >> 7, c = tid & 127;        // half, float4-col
    const float4* x4 = (const float4*)(x + (size_t)blk * NC2 * D_DIM);
    float4 a = {0.f, 0.f, 0.f, 0.f};
    #pragma unroll
    for (int rp = 0; rp < NC2 / 2; ++rp) {        // clean streaming sum
      float4 v = x4[(rp * 2 + h) * 128 + c];
      a.x += v.x; a.y += v.y; a.z += v.z; a.w += v.w;
    }
    if (h) oddsum[c] = a;
    __syncthreads();
    if (!h) {
      float4 b = oddsum[c];
      bf16x4 o = { (bf16_t)(a.x + b.x), (bf16_t)(a.y + b.y),
                   (bf16_t)(a.z + b.z), (bf16_t)(a.w + b.w) };
      *(bf16x4*)(Sbf + (size_t)blk * D_DIM + c * 4) = o;
    }
  } else {
    __shared__ float tile[32][33];
    const int t = blk - B_SAMP;
    const float* W  = (t & 256) ? Wnbr : Wself;
    bf16_t*     Wt  = (t & 256) ? Wnt  : Wst;
    const int r = t & 255;
    const int k0 = (r & 15) * 32, n0 = (r >> 4) * 32;
    const int tx = tid & 31, ty = tid >> 5;
    #pragma unroll
    for (int i = 0; i < 32; i += 8)
      tile[ty + i][tx] = W[(size_t)(k0 + ty + i) * D_DIM + n0 + tx];
    __syncthreads();
    #pragma unroll
    for (int i = 0; i < 32; i += 8)
      Wt[(size_t)(n0 + ty + i) * D_DIM + k0 + tx] = (bf16_t)tile[tx][ty + i];
  }
}

// --- K2: fused GEMM, A direct-from-x reg-staged, B gload_lds, dbuf ---------
// Block (bx, by): 8 samples, out rows [bx*80, +80), cols [by*64, +64).
// A-LDS chunks (16B): LDS[row][c] = src[row][c ^ ((row>>1)&3)]  (involution,
// applied on BOTH write (reg-staged) and read sides).
#define SA_BYTES 6144              // 96 rows * 64 B
#define SB_BYTES 8192              // 2 mats * 64 rows * 64 B
__global__ __launch_bounds__(256) void fused_gemm_kernel(
    const float* __restrict__ x, const bf16_t* __restrict__ Sbf,
    const bf16_t* __restrict__ Wst, const bf16_t* __restrict__ Wnt,
    const int* __restrict__ pairs, const float* __restrict__ bias,
    float* __restrict__ out)
{
  __shared__ __align__(16) unsigned char pool[2 * SA_BYTES + 2 * SB_BYTES];
  __shared__ int xrow[80];

  const int tid = threadIdx.x;
  const int w = tid >> 6, l = tid & 63;
  const int kg = l >> 4, lr = l & 15;
  const int n0 = blockIdx.y * 64;              // block col base
  const int n0w = n0 + w * 16;                 // wave col base
  const int arow0 = blockIdx.x * 80;
  const int srow0 = blockIdx.x * 8;

  // per-block gather lut: x row index for each of the 80 rel rows
  if (tid < 80) {
    int sm = srow0 + tid / MAXREL, j = tid % MAXREL;
    int p0 = pairs[(size_t)(sm * MAXREL + j) * 2 + 0];
    int p1 = pairs[(size_t)(sm * MAXREL + j) * 2 + 1];
    int pmin = min(p0, p1), pmax = max(p0, p1);
    xrow[tid] = sm * NC2 + 7 * pmin - (pmin * (pmin - 1)) / 2 + (pmax - pmin - 1);
  }
  __syncthreads();

  f32x4 acc[6] = {};

  // stage one 32-wide K slab into buffer bsel:
  //  A: 96 rows x 8 quads(4 elems) = 768 items, reg-staged (x f32 -> bf16,
  //     Sbf bf16 passthrough), swizzled ds_write. 3 items/thread.
  //  B: 512 x 16B chunks via gload_lds, 2/thread (R5-proven pattern).
  auto STAGE = [&](int bsel, int k0) {
    bf16_t* aB = (bf16_t*)(pool + bsel * SA_BYTES);
    bf16_t* bB = (bf16_t*)(pool + 2 * SA_BYTES + bsel * SB_BYTES);
    #pragma unroll
    for (int r = 0; r < 2; ++r) {              // B first: async, no regs held
      int bslot = r * 4 + w;                   // 0..7, 64 chunks each
      int c = bslot * 64 + l;
      int mat = c >> 8, rc = c & 255;
      int row = rc >> 2, ch = rc & 3;
      int sch = ch ^ ((row >> 1) & 3);
      const bf16_t* W = mat ? Wnt : Wst;
      gload_lds16(W + (size_t)(n0 + row) * D_DIM + k0 + sch * 8,
                  bB + (size_t)c * 8);
    }
    #pragma unroll
    for (int r = 0; r < 3; ++r) {              // A reg-staged
      int idx = r * 256 + tid;                 // 0..767
      int row = idx >> 3, kq = idx & 7;        // row 0..95, 4-elem quad 0..7
      int slot8 = (((kq >> 1) ^ ((row >> 1) & 3)) << 1) + (kq & 1);
      bf16x4 val;
      if (row < 80) {
        float4 v = *(const float4*)(x + (size_t)xrow[row] * D_DIM + k0 + kq * 4);
        val = bf16x4{ (bf16_t)v.x, (bf16_t)v.y, (bf16_t)v.z, (bf16_t)v.w };
      } else {
        val = *(const bf16x4*)(Sbf + (size_t)(srow0 + (row & 7)) * D_DIM + k0 + kq * 4);
      }
      *(bf16x4*)(aB + row * 32 + slot8 * 4) = val;
    }
  };

  STAGE(0, 0);
  __syncthreads();

  const int xorc = (kg ^ ((lr >> 1) & 3)) * 8;   // swizzled chunk -> elem off
  int cur = 0;
  #pragma unroll 2
  for (int t = 0; t < 16; ++t) {
    if (t < 15) STAGE(cur ^ 1, (t + 1) * 32);    // prefetch next slab

    const bf16_t* aC = (const bf16_t*)(pool + cur * SA_BYTES);
    const bf16_t* bC = (const bf16_t*)(pool + 2 * SA_BYTES + cur * SB_BYTES);
    bf16x8 af[6], bs, bn;
    #pragma unroll
    for (int s = 0; s < 6; ++s)
      af[s] = *(const bf16x8*)(aC + (s * 16 + lr) * 32 + xorc);
    bs = *(const bf16x8*)(bC + (w * 16 + lr) * 32 + xorc);
    bn = *(const bf16x8*)(bC + 2048 + (w * 16 + lr) * 32 + xorc);

    #pragma unroll
    for (int s = 0; s < 5; ++s)
      acc[s] = __builtin_amdgcn_mfma_f32_16x16x32_bf16(af[s], bs, acc[s], 0, 0, 0);
    acc[5] = __builtin_amdgcn_mfma_f32_16x16x32_bf16(af[5], bn, acc[5], 0, 0, 0);

    __syncthreads();   // drains staging + fences LDS reads (TLP hides it)
    cur ^= 1;
  }

  // T tile -> per-wave LDS region (pool reuse; fenced by final barrier).
  // C/D layout: col = l&15, row = (l>>4)*4 + reg; strip-5 rows 8..15 dup 0..7.
  float* Tex = (float*)pool;                     // [4 waves][8][20]
  #pragma unroll
  for (int reg = 0; reg < 4; ++reg)
    Tex[(w * 8 + ((kg * 4 + reg) & 7)) * 20 + lr] = acc[5][reg];
  __syncthreads();

  const float bv = bias[n0w + lr];
  #pragma unroll
  for (int s = 0; s < 5; ++s) {
    #pragma unroll
    for (int reg = 0; reg < 4; ++reg) {
      int rloc = s * 16 + kg * 4 + reg;          // 0..79
      int ls = rloc / MAXREL;                    // local sample 0..7
      float v = acc[s][reg] + Tex[(w * 8 + ls) * 20 + lr] + bv;
      out[(size_t)(arow0 + rloc) * D_DIM + n0w + lr] = fmaxf(v, 0.0f);
    }
  }
}

extern "C" void kernel_launch(void* const* d_in, const int* in_sizes, int n_in,
                              void* d_out, int out_size, void* d_ws, size_t ws_size,
                              hipStream_t stream) {
  const float* x     = (const float*)d_in[0];   // [28672, 512]
  const float* Wself = (const float*)d_in[1];   // [512, 512]
  const float* Wnbr  = (const float*)d_in[2];   // [512, 512]
  const float* bias  = (const float*)d_in[3];   // [512]
  const int*   pairs = (const int*)d_in[5];     // [1024, 10, 2]

  char* ws = (char*)d_ws;
  size_t off = 0;
  bf16_t* Sbf = (bf16_t*)(ws + off); off += (size_t)B_SAMP * D_DIM * 2;
  bf16_t* Wst = (bf16_t*)(ws + off); off += (size_t)D_DIM * D_DIM * 2;
  bf16_t* Wnt = (bf16_t*)(ws + off); off += (size_t)D_DIM * D_DIM * 2;

  prep_kernel<<<B_SAMP + 512, 256, 0, stream>>>(x, Wself, Wnbr, Sbf, Wst, Wnt);
  fused_gemm_kernel<<<dim3(OUTROWS / 80, D_DIM / 64), 256, 0, stream>>>(
      x, Sbf, Wst, Wnt, pairs, bias, (float*)d_out);
}

// Round 11
// 32.738 us; speedup vs baseline: 1.3869x; 1.3869x over previous
//
#include <hip/hip_runtime.h>
#include <hip/hip_bf16.h>
#include <stdint.h>

// ---------------------------------------------------------------------------
// GraphicalBranch: out[r] = relu(x[row_r] @ W_self + (S_{b_r} @ W_nbr) + bias)
//   S_b = sum of the 28 pair-node rows of sample b
//   row_r = b*28 + pidx(pmin,pmax), pidx = 7i - i(i-1)/2 + (j-i-1)  [analytic]
// K1 prep (1536 blks): streaming S-sum + L2-hot gather->Abf | W^T in
//   MFMA-FRAGMENT-MAJOR layout: cell (cf,t) = 64 lanes x 16B, lane l elem e =
//   W[k = t*32+(l>>4)*8+e][col = cf*16+(l&15)]  -> GEMM B-load is one
//   fully-coalesced dwordx4 per wave (1 KB), no LDS staging for B.
// K2 fused GEMM (128x8 blks, 64-col tiles, 12.3KB LDS):
//   A (5 rel strips + S strip) via global_load_lds + XOR swizzle, dbuf;
//   B direct global->reg from frag-major W (X/Y named-reg dbuf, L2-hot);
//   epilogue out = relu(acc + T[sample] + bias).
// ---------------------------------------------------------------------------

typedef __bf16 bf16_t;
typedef __bf16 bf16x8 __attribute__((ext_vector_type(8)));
typedef __bf16 bf16x4 __attribute__((ext_vector_type(4)));
typedef float  f32x4  __attribute__((ext_vector_type(4)));

#define D_DIM 512
#define NC2   28
#define NOBJ  8
#define MAXREL 10
#define B_SAMP 1024
#define OUTROWS (B_SAMP * MAXREL)

__device__ __forceinline__ void gload_lds16(const void* g, void* l) {
  __builtin_amdgcn_global_load_lds(
      (const __attribute__((address_space(1))) unsigned int*)g,
      (__attribute__((address_space(3))) unsigned int*)l, 16, 0, 0);
}

// --- K1: fused prep --------------------------------------------------------
// blocks [0,1024):     S[b] = sum of 28 rows (streaming float4) -> bf16;
//                      then gather the 10 rel rows (L1/L2-hot) -> Abf
// blocks [1024,1536):  W -> bf16 fragment-major (256 blocks per matrix)
__global__ __launch_bounds__(256) void prep_kernel(
    const float* __restrict__ x, const float* __restrict__ Wself,
    const float* __restrict__ Wnbr, const int* __restrict__ pairs,
    bf16_t* __restrict__ Sbf, bf16_t* __restrict__ Abf,
    bf16_t* __restrict__ Wsf, bf16_t* __restrict__ Wnf)
{
  const int blk = blockIdx.x, tid = threadIdx.x;
  if (blk < B_SAMP) {
    __shared__ int rel_row[MAXREL];
    __shared__ float4 oddsum[128];
    if (tid < MAXREL) {
      int p0 = pairs[blk * MAXREL * 2 + tid * 2 + 0];
      int p1 = pairs[blk * MAXREL * 2 + tid * 2 + 1];
      int pmin = min(p0, p1), pmax = max(p0, p1);
      rel_row[tid] = 7 * pmin - (pmin * (pmin - 1)) / 2 + (pmax - pmin - 1);
    }
    __syncthreads();

    const int h = tid >> 7, c = tid & 127;        // half, float4-col
    const float4* x4 = (const float4*)(x + (size_t)blk * NC2 * D_DIM);
    float4 a = {0.f, 0.f, 0.f, 0.f};
    #pragma unroll
    for (int rp = 0; rp < NC2 / 2; ++rp) {        // clean streaming sum
      float4 v = x4[(rp * 2 + h) * 128 + c];
      a.x += v.x; a.y += v.y; a.z += v.z; a.w += v.w;
    }
    if (h) oddsum[c] = a;
    __syncthreads();
    if (!h) {
      float4 b = oddsum[c];
      bf16x4 o = { (bf16_t)(a.x + b.x), (bf16_t)(a.y + b.y),
                   (bf16_t)(a.z + b.z), (bf16_t)(a.w + b.w) };
      *(bf16x4*)(Sbf + (size_t)blk * D_DIM + c * 4) = o;
    }
    // gather pass: rows just streamed -> L1/L2 hot
    #pragma unroll
    for (int j = h; j < MAXREL; j += 2) {
      float4 v = x4[rel_row[j] * 128 + c];
      bf16x4 o = { (bf16_t)v.x, (bf16_t)v.y, (bf16_t)v.z, (bf16_t)v.w };
      *(bf16x4*)(Abf + (size_t)(blk * MAXREL + j) * D_DIM + c * 4) = o;
    }
  } else {
    __shared__ float tile[32 * 33];
    const int r = blk - B_SAMP;                   // 0..511
    const float* W  = (r & 256) ? Wnbr : Wself;
    bf16_t*     Wf  = (r & 256) ? Wnf  : Wsf;
    const int piece = r & 255;
    const int tstep = piece & 15, nblk = piece >> 4;
    const int k0 = tstep * 32, n0 = nblk * 32;
    const int tx = tid & 31, ty = tid >> 5;
    #pragma unroll
    for (int i = 0; i < 32; i += 8)
      tile[(ty + i) * 33 + tx] = W[(size_t)(k0 + ty + i) * D_DIM + n0 + tx];
    __syncthreads();
    // frag write: thread -> (cf_local, lane, elem-half); stores are
    // tid-contiguous 8B -> fully coalesced 2KB per block
    const int cfl = tid >> 7, rem = tid & 127;
    const int ll = rem >> 1, eh = rem & 1;
    const int kb = (ll >> 4) * 8 + eh * 4;        // k_local base
    const int nl = cfl * 16 + (ll & 15);          // n_local
    bf16x4 o = { (bf16_t)tile[(kb + 0) * 33 + nl], (bf16_t)tile[(kb + 1) * 33 + nl],
                 (bf16_t)tile[(kb + 2) * 33 + nl], (bf16_t)tile[(kb + 3) * 33 + nl] };
    const int cf = nblk * 2 + cfl;
    *(bf16x4*)(Wf + ((size_t)(cf * 16 + tstep) * 64 + ll) * 8 + eh * 4) = o;
  }
}

// --- K2: fused GEMM, A-LDS dbuf + frag-major B direct-to-reg ---------------
// Block (bx, by): 8 samples, out rows [bx*80, +80), cols [by*64, +64).
// A strips 0..4 = 80 rel rows (@Wself); strip 5 = 8 S rows dup (@Wnbr -> T).
// Wave w owns cols [by*64 + w*16, +16)  (cf = by*4 + w).
// A-LDS chunks (16B): LDS[row][c] = G[row][c ^ ((row>>1)&3)]  (involution).
#define SA_BYTES 6144              // 96 rows * 64 B

#define DO_STEP(BS, BN) do {                                                  \
    const bf16_t* aC = (const bf16_t*)(pool + cur * SA_BYTES);                \
    bf16x8 af[6];                                                             \
    _Pragma("unroll")                                                         \
    for (int s_ = 0; s_ < 6; ++s_)                                            \
      af[s_] = *(const bf16x8*)(aC + (s_ * 16 + lr) * 32 + xorc);             \
    _Pragma("unroll")                                                         \
    for (int s_ = 0; s_ < 5; ++s_)                                            \
      acc[s_] = __builtin_amdgcn_mfma_f32_16x16x32_bf16(af[s_], BS, acc[s_], 0, 0, 0); \
    acc[5] = __builtin_amdgcn_mfma_f32_16x16x32_bf16(af[5], BN, acc[5], 0, 0, 0); \
  } while (0)

__global__ __launch_bounds__(256, 5) void fused_gemm_kernel(
    const bf16_t* __restrict__ Abf, const bf16_t* __restrict__ Sbf,
    const bf16_t* __restrict__ Wsf, const bf16_t* __restrict__ Wnf,
    const float* __restrict__ bias, float* __restrict__ out)
{
  __shared__ __align__(16) unsigned char pool[2 * SA_BYTES];

  const int tid = threadIdx.x;
  const int w = tid >> 6, l = tid & 63;
  const int kg = l >> 4, lr = l & 15;
  const int n0w = blockIdx.y * 64 + w * 16;    // wave col base
  const int arow0 = blockIdx.x * 80;
  const int srow0 = blockIdx.x * 8;
  const int cf = blockIdx.y * 4 + w;           // wave's col-frag index

  // frag-major B streams: step t at +t*512 elems (1KB coalesced per wave)
  const bf16_t* pBs = Wsf + (size_t)cf * 16 * 512 + (size_t)l * 8;
  const bf16_t* pBn = Wnf + (size_t)cf * 16 * 512 + (size_t)l * 8;

  f32x4 acc[6] = {};

  // stage A slab (96 rows x 32 k = 384 x 16B chunks): w0,w1 -> 2; w2,w3 -> 1
  auto STAGE = [&](int bsel, int k0) {
    bf16_t* aB = (bf16_t*)(pool + bsel * SA_BYTES);
    #pragma unroll
    for (int r = 0; r < 2; ++r) {
      int slot = r * 4 + w;
      if (slot < 6) {
        int c = slot * 64 + l;
        int row = c >> 2, ch = c & 3;
        int sch = ch ^ ((row >> 1) & 3);
        const bf16_t* g = (row < 80)
            ? Abf + (size_t)(arow0 + row) * D_DIM + k0 + sch * 8
            : Sbf + (size_t)(srow0 + (row & 7)) * D_DIM + k0 + sch * 8;
        gload_lds16(g, aB + (size_t)c * 8);
      }
    }
  };

  bf16x8 bsX, bnX, bsY, bnY;
  STAGE(0, 0);
  bsX = *(const bf16x8*)(pBs);
  bnX = *(const bf16x8*)(pBn);
  __syncthreads();                               // drains stage + B t=0

  const int xorc = (kg ^ ((lr >> 1) & 3)) * 8;   // swizzled chunk -> elem off
  int cur = 0;
  #pragma unroll
  for (int t = 0; t < 16; t += 2) {
    // even step: compute cur with X; prefetch t+1 (A -> cur^1, B -> Y)
    if (t + 1 < 16) {
      STAGE(cur ^ 1, (t + 1) * 32);
      bsY = *(const bf16x8*)(pBs + (t + 1) * 512);
      bnY = *(const bf16x8*)(pBn + (t + 1) * 512);
    }
    DO_STEP(bsX, bnX);
    __syncthreads();                             // prefetch had full step to land
    cur ^= 1;

    // odd step: compute cur with Y; prefetch t+2 (A -> cur^1, B -> X)
    if (t + 2 < 16) {
      STAGE(cur ^ 1, (t + 2) * 32);
      bsX = *(const bf16x8*)(pBs + (t + 2) * 512);
      bnX = *(const bf16x8*)(pBn + (t + 2) * 512);
    }
    DO_STEP(bsY, bnY);
    __syncthreads();
    cur ^= 1;
  }

  // T tile -> per-wave LDS region (pool reuse; fenced by final barrier).
  // C/D layout: col = l&15, row = (l>>4)*4 + reg; strip-5 rows 8..15 dup 0..7.
  float* Tex = (float*)pool;                     // [4 waves][8][20]
  #pragma unroll
  for (int reg = 0; reg < 4; ++reg)
    Tex[(w * 8 + ((kg * 4 + reg) & 7)) * 20 + lr] = acc[5][reg];
  __syncthreads();

  const float bv = bias[n0w + lr];
  #pragma unroll
  for (int s = 0; s < 5; ++s) {
    #pragma unroll
    for (int reg = 0; reg < 4; ++reg) {
      int rloc = s * 16 + kg * 4 + reg;          // 0..79
      int ls = rloc / MAXREL;                    // local sample 0..7
      float v = acc[s][reg] + Tex[(w * 8 + ls) * 20 + lr] + bv;
      out[(size_t)(arow0 + rloc) * D_DIM + n0w + lr] = fmaxf(v, 0.0f);
    }
  }
}

extern "C" void kernel_launch(void* const* d_in, const int* in_sizes, int n_in,
                              void* d_out, int out_size, void* d_ws, size_t ws_size,
                              hipStream_t stream) {
  const float* x     = (const float*)d_in[0];   // [28672, 512]
  const float* Wself = (const float*)d_in[1];   // [512, 512]
  const float* Wnbr  = (const float*)d_in[2];   // [512, 512]
  const float* bias  = (const float*)d_in[3];   // [512]
  const int*   pairs = (const int*)d_in[5];     // [1024, 10, 2]

  char* ws = (char*)d_ws;
  size_t off = 0;
  bf16_t* Sbf = (bf16_t*)(ws + off); off += (size_t)B_SAMP * D_DIM * 2;
  bf16_t* Wsf = (bf16_t*)(ws + off); off += (size_t)D_DIM * D_DIM * 2;
  bf16_t* Wnf = (bf16_t*)(ws + off); off += (size_t)D_DIM * D_DIM * 2;
  bf16_t* Abf = (bf16_t*)(ws + off); off += (size_t)OUTROWS * D_DIM * 2;

  prep_kernel<<<B_SAMP + 512, 256, 0, stream>>>(
      x, Wself, Wnbr, pairs, Sbf, Abf, Wsf, Wnf);
  fused_gemm_kernel<<<dim3(OUTROWS / 80, D_DIM / 64), 256, 0, stream>>>(
      Abf, Sbf, Wsf, Wnf, bias, (float*)d_out);
}